// Round 24
// baseline (134.752 us; speedup 1.0000x reference)
//
#include <hip/hip_runtime.h>

typedef float f32x16 __attribute__((ext_vector_type(16)));
typedef float f32x4  __attribute__((ext_vector_type(4)));
typedef short s16x8  __attribute__((ext_vector_type(8)));
typedef short s16x4  __attribute__((ext_vector_type(4)));

constexpr int Bn = 2, Tn = 2048, Dn = 768, Hn = 12, DHn = 64;
constexpr int NX = Bn * Tn * Dn;   // 3,145,728
constexpr int NW = Dn * Dn;        // 589,824
constexpr float SC2f = 0.125f * 1.44269504088896f;  // (1/sqrt(64))*log2(e)

__device__ __forceinline__ unsigned short f2bf(float f) {
    union { float f; unsigned int i; } c; c.f = f;
    unsigned int u = c.i;
    u += 0x7fffu + ((u >> 16) & 1u);
    return (unsigned short)(u >> 16);
}
__device__ __forceinline__ unsigned int cvtpk(float lo, float hi) {
    unsigned int r;
    asm("v_cvt_pk_bf16_f32 %0, %1, %2" : "=v"(r) : "v"(lo), "v"(hi));
    return r;
}
// load 8 f32 and convert to 8 bf16 in-register (RNE via cvt_pk)
__device__ __forceinline__ s16x8 ld_cvt(const float* p) {
    f32x4 a = *(const f32x4*)p;
    f32x4 b = *(const f32x4*)(p + 4);
    union { unsigned int u[4]; s16x8 v; } r;
    r.u[0] = cvtpk(a[0], a[1]); r.u[1] = cvtpk(a[2], a[3]);
    r.u[2] = cvtpk(b[0], b[1]); r.u[3] = cvtpk(b[2], b[3]);
    return r.v;
}
__device__ __forceinline__ void barrier_lgkm() {
    asm volatile("s_waitcnt lgkmcnt(0)" ::: "memory");
    __builtin_amdgcn_s_barrier();
    asm volatile("" ::: "memory");
}

// ---- LDS-staged QKV projection from f32 inputs (cvt fused in staging):
// 128x128 tile, BK=32, double-buffered.
// z=0: Q row-layout [bh][t][dh] (scaled). z=1: K in MFMA-FRAGMENT order
// Kf[bh][kt][c][lane][8]. z=2: V in fragment order Vf[bh][kt][c2][o][lane][8].
__global__ __launch_bounds__(256) void proj_staged(
    const float* __restrict__ x,
    const float* __restrict__ wq, const float* __restrict__ wk,
    const float* __restrict__ wv,
    const float* __restrict__ bq, const float* __restrict__ bk,
    const float* __restrict__ bv,
    unsigned short* __restrict__ qo, unsigned short* __restrict__ kfo,
    unsigned short* __restrict__ vfo)
{
    __shared__ unsigned short lA[2][128 * 40];
    __shared__ unsigned short lB[2][128 * 40];

    const int z = blockIdx.z;
    const bool vt = (z == 2);
    const float* W = (z == 0) ? wq : (z == 1) ? wk : wv;
    const float* bias = (z == 0) ? bq : (z == 1) ? bk : bv;
    const int tid = threadIdx.x, lane = tid & 63, wid = tid >> 6;
    const int lq = lane & 31, g = lane >> 5;
    const int mb = vt ? blockIdx.y : blockIdx.x;
    const int nb = vt ? blockIdx.x : blockIdx.y;
    const float* Am = vt ? W : x;
    const float* Bm = vt ? x : W;

    const int srow = tid >> 2, sch = tid & 3;
    const float* ag0 = Am + (size_t)(mb * 128 +      srow) * Dn + sch * 8;
    const float* ag1 = Am + (size_t)(mb * 128 + 64 + srow) * Dn + sch * 8;
    const float* bg0 = Bm + (size_t)(nb * 128 +      srow) * Dn + sch * 8;
    const float* bg1 = Bm + (size_t)(nb * 128 + 64 + srow) * Dn + sch * 8;
    const int sd0 = srow * 40 + sch * 8;
    const int sd1 = (64 + srow) * 40 + sch * 8;

    f32x16 acc[2][2];
#pragma unroll
    for (int am = 0; am < 2; ++am)
#pragma unroll
        for (int bn = 0; bn < 2; ++bn)
#pragma unroll
            for (int i = 0; i < 16; ++i) acc[am][bn][i] = 0.f;

    {
        s16x8 a0 = ld_cvt(ag0), a1 = ld_cvt(ag1);
        s16x8 b0 = ld_cvt(bg0), b1 = ld_cvt(bg1);
        *(s16x8*)&lA[0][sd0] = a0; *(s16x8*)&lA[0][sd1] = a1;
        *(s16x8*)&lB[0][sd0] = b0; *(s16x8*)&lB[0][sd1] = b1;
    }
    const int ar = (wid & 1) * 64 + lq;
    const int br = (wid >> 1) * 64 + lq;

    for (int kt = 0; kt < 24; ++kt) {
        const int cur = kt & 1;
        s16x8 a0, a1, b0, b1;
        if (kt < 23) {
            a0 = ld_cvt(ag0 + (kt + 1) * 32);
            a1 = ld_cvt(ag1 + (kt + 1) * 32);
            b0 = ld_cvt(bg0 + (kt + 1) * 32);
            b1 = ld_cvt(bg1 + (kt + 1) * 32);
        }
        barrier_lgkm();
        s16x8 afr[2][2], bfr[2][2];
#pragma unroll
        for (int am = 0; am < 2; ++am)
#pragma unroll
            for (int kc = 0; kc < 2; ++kc)
                afr[am][kc] = *(const s16x8*)&lA[cur][(ar + am * 32) * 40 + (2 * kc + g) * 8];
#pragma unroll
        for (int bn = 0; bn < 2; ++bn)
#pragma unroll
            for (int kc = 0; kc < 2; ++kc)
                bfr[bn][kc] = *(const s16x8*)&lB[cur][(br + bn * 32) * 40 + (2 * kc + g) * 8];
#pragma unroll
        for (int kc = 0; kc < 2; ++kc)
#pragma unroll
            for (int am = 0; am < 2; ++am)
#pragma unroll
                for (int bn = 0; bn < 2; ++bn)
                    acc[am][bn] = __builtin_amdgcn_mfma_f32_32x32x16_bf16(
                        afr[am][kc], bfr[bn][kc], acc[am][bn], 0, 0, 0);
        if (kt < 23) {
            *(s16x8*)&lA[cur ^ 1][sd0] = a0; *(s16x8*)&lA[cur ^ 1][sd1] = a1;
            *(s16x8*)&lB[cur ^ 1][sd0] = b0; *(s16x8*)&lB[cur ^ 1][sd1] = b1;
        }
    }

    if (z == 0) {          // Q: row layout, pre-scaled
#pragma unroll
        for (int bn = 0; bn < 2; ++bn) {
            const int e = nb * 128 + (wid >> 1) * 64 + bn * 32 + lq;
            const float bvl = bias[e];
            const int h = e >> 6, dh = e & 63;
#pragma unroll
            for (int am = 0; am < 2; ++am)
#pragma unroll
                for (int r = 0; r < 16; ++r) {
                    const int t = mb * 128 + (wid & 1) * 64 + am * 32 + ((r & 3) + 8 * (r >> 2) + 4 * g);
                    const int b = t >> 11, tl = t & (Tn - 1);
                    qo[((size_t)(b * Hn + h) * Tn + tl) * DHn + dh] = f2bf((acc[am][bn][r] + bvl) * SC2f);
                }
        }
    } else if (z == 1) {   // K: fragment order
#pragma unroll
        for (int bn = 0; bn < 2; ++bn) {
            const int e = nb * 128 + (wid >> 1) * 64 + bn * 32 + lq;
            const float bvl = bias[e];
            const int h = e >> 6, dh = e & 63;
            const int cK = dh >> 4, gK = (dh >> 3) & 1, el = dh & 7;
#pragma unroll
            for (int am = 0; am < 2; ++am)
#pragma unroll
                for (int r = 0; r < 16; ++r) {
                    const int t = mb * 128 + (wid & 1) * 64 + am * 32 + ((r & 3) + 8 * (r >> 2) + 4 * g);
                    const int b = t >> 11, tl = t & (Tn - 1);
                    const int kt2 = tl >> 5, lrow = tl & 31;
                    kfo[(((size_t)(b * Hn + h) * 64 + kt2) * 4 + cK) * 512
                        + (lrow + 32 * gK) * 8 + el] = f2bf(acc[am][bn][r] + bvl);
                }
        }
    } else {               // V: fragment order (values are V^T[e][t])
#pragma unroll
        for (int am = 0; am < 2; ++am)
#pragma unroll
            for (int r = 0; r < 16; ++r) {
                const int e = mb * 128 + (wid & 1) * 64 + am * 32 + ((r & 3) + 8 * (r >> 2) + 4 * g);
                const float bvl = bias[e];
                const int h = e >> 6, dhp = e & 63;
                const int o = dhp >> 5, lqv = dhp & 31;
#pragma unroll
                for (int bn = 0; bn < 2; ++bn) {
                    const int t = nb * 128 + (wid >> 1) * 64 + bn * 32 + lq;
                    const int b = t >> 11, tl = t & (Tn - 1);
                    const int kt2 = tl >> 5, kcol = tl & 31;
                    const int c2 = kcol >> 4, rem = kcol & 15;
                    const int gV = (rem >> 2) & 1;
                    const int j = (rem & 3) + ((rem >> 3) << 2);
                    vfo[((((size_t)(b * Hn + h) * 64 + kt2) * 2 + c2) * 2 + o) * 512
                        + (lqv + 32 * gV) * 8 + j] = f2bf(acc[am][bn][r] + bvl);
                }
            }
    }
}

// ---- main attention: prepass + double-buffered panel NT writes, with
// cross-tile K REGISTER PREFETCH (loads for kt+4 issued before computing kt
// -> L2 latency hides under MFMA/exp2/PV; the barrier otherwise blocks the
// compiler from hoisting them). V loads issued at top of tile body.
__global__ __launch_bounds__(256) void attn_main(
    const unsigned short* __restrict__ Q,   // [BH][T][Dh], pre-scaled
    const unsigned short* __restrict__ Kf,  // [BH][64][4][64][8] frag order
    const unsigned short* __restrict__ Vf,  // [BH][64][2][2][64][8] frag order
    float* __restrict__ heads,              // [B][T][H][Dh]
    float* __restrict__ attn)               // [BH][T][T]
{
    __shared__ float P2[8192];              // 2 x 16KB panels; O-combine overlay
    __shared__ float pls[4][32];

    const int tid = threadIdx.x, lane = tid & 63, wid = tid >> 6;
    const int lq = lane & 31, g = lane >> 5;
    // 1536 blocks: XCD k owns heads [3k,3k+3); longest strips first.
    const int n2 = ((int)blockIdx.x & 7) * 192 + ((int)blockIdx.x >> 3);
    const int bh = n2 >> 6;
    const int s  = 63 - (n2 & 63);
    const int qbase = s * 32;

    const unsigned short* Qb = Q  + ((size_t)bh * Tn + qbase) * DHn;
    const unsigned short* Kb = Kf + (size_t)bh * 131072 + lane * 8;
    const unsigned short* Vb = Vf + (size_t)bh * 131072 + lane * 8;
    const int swz = (lq & 7) << 2;

    s16x8 qf[4];
#pragma unroll
    for (int c = 0; c < 4; ++c)
        qf[c] = *(const s16x8*)(Qb + lq * DHn + c * 16 + g * 8);

    // ---- prepass: block-local softmax denominator (K prefetched) ----
    float ls = 0.f;
    {
        s16x8 kcur[4];
        if (wid <= s) {
            const unsigned short* kb = Kb + (size_t)wid * 2048;
#pragma unroll
            for (int c = 0; c < 4; ++c) kcur[c] = *(const s16x8*)(kb + c * 512);
        }
        for (int kt = wid; kt <= s; kt += 4) {
            s16x8 knx[4];
            if (kt + 4 <= s) {
                const unsigned short* kb = Kb + (size_t)(kt + 4) * 2048;
#pragma unroll
                for (int c = 0; c < 4; ++c) knx[c] = *(const s16x8*)(kb + c * 512);
            }
            f32x16 acc;
#pragma unroll
            for (int i = 0; i < 16; ++i) acc[i] = 0.f;
#pragma unroll
            for (int c = 0; c < 4; ++c)
                acc = __builtin_amdgcn_mfma_f32_32x32x16_bf16(kcur[c], qf[c], acc, 0, 0, 0);
            if (kt == s) {      // wave-uniform: only the diagonal tile masks
#pragma unroll
                for (int r = 0; r < 16; ++r) {
                    const int koff = (r & 3) + 8 * (r >> 2) + 4 * g;
                    ls += (koff <= lq) ? exp2f(acc[r]) : 0.f;
                }
            } else {
#pragma unroll
                for (int r = 0; r < 16; ++r) ls += exp2f(acc[r]);
            }
#pragma unroll
            for (int c = 0; c < 4; ++c) kcur[c] = knx[c];
        }
    }
    ls += __shfl_xor(ls, 32);
    if (g == 0) pls[wid][lq] = ls;
    __syncthreads();
    const float rl = 1.f / (pls[0][lq] + pls[1][lq] + pls[2][lq] + pls[3][lq]);

    f32x16 o0, o1;
#pragma unroll
    for (int i = 0; i < 16; ++i) { o0[i] = 0.f; o1[i] = 0.f; }

    // ---- main loop: 16 panels x 4 tiles, double-buffered, K prefetched ----
    s16x8 kcur[4];
    if (wid <= s) {
        const unsigned short* kb = Kb + (size_t)wid * 2048;
#pragma unroll
        for (int c = 0; c < 4; ++c) kcur[c] = *(const s16x8*)(kb + c * 512);
    }
    for (int p = 0; p < 16; ++p) {
        float* buf = P2 + (p & 1) * 4096;
        const int kt = p * 4 + wid;       // this wave's tile; slot == wid
        if (kt <= s) {
            // V loads for current tile + K prefetch for next, issued early
            const unsigned short* vb = Vb + (size_t)kt * 2048;
            s16x8 v00 = *(const s16x8*)(vb + 0);
            s16x8 v01 = *(const s16x8*)(vb + 512);
            s16x8 v10 = *(const s16x8*)(vb + 1024);
            s16x8 v11 = *(const s16x8*)(vb + 1536);
            s16x8 knx[4];
            if (kt + 4 <= s) {
                const unsigned short* kb = Kb + (size_t)(kt + 4) * 2048;
#pragma unroll
                for (int c = 0; c < 4; ++c) knx[c] = *(const s16x8*)(kb + c * 512);
            }
            f32x16 acc;
#pragma unroll
            for (int i = 0; i < 16; ++i) acc[i] = 0.f;
#pragma unroll
            for (int c = 0; c < 4; ++c)
                acc = __builtin_amdgcn_mfma_f32_32x32x16_bf16(kcur[c], qf[c], acc, 0, 0, 0);
            float pv[16];
            if (kt == s) {  // wave-uniform diag branch: mask only here
#pragma unroll
                for (int r = 0; r < 16; ++r) {
                    const int koff = (r & 3) + 8 * (r >> 2) + 4 * g;
                    pv[r] = (koff <= lq) ? exp2f(acc[r]) * rl : 0.f;
                }
            } else {
#pragma unroll
                for (int r = 0; r < 16; ++r) pv[r] = exp2f(acc[r]) * rl;
            }
            // P-tile into panel slot wid (row lq, swizzled within 32-col slot)
#pragma unroll
            for (int a = 0; a < 4; ++a) {
                f32x4 w;
                w[0]=pv[4*a+0]; w[1]=pv[4*a+1]; w[2]=pv[4*a+2]; w[3]=pv[4*a+3];
                *(f32x4*)&buf[lq * 128 + wid * 32 + ((4 * g + 8 * a) ^ swz)] = w;
            }
            // PV: P (bf16) via cvt_pk; V fragments pre-packed
            union { unsigned int uu[4]; s16x8 v; } P0, P1;
            P0.uu[0]=cvtpk(pv[0],pv[1]);   P0.uu[1]=cvtpk(pv[2],pv[3]);
            P0.uu[2]=cvtpk(pv[4],pv[5]);   P0.uu[3]=cvtpk(pv[6],pv[7]);
            P1.uu[0]=cvtpk(pv[8],pv[9]);   P1.uu[1]=cvtpk(pv[10],pv[11]);
            P1.uu[2]=cvtpk(pv[12],pv[13]); P1.uu[3]=cvtpk(pv[14],pv[15]);
            o0 = __builtin_amdgcn_mfma_f32_32x32x16_bf16(P0.v, v00, o0, 0, 0, 0);
            o1 = __builtin_amdgcn_mfma_f32_32x32x16_bf16(P0.v, v01, o1, 0, 0, 0);
            o0 = __builtin_amdgcn_mfma_f32_32x32x16_bf16(P1.v, v10, o0, 0, 0, 0);
            o1 = __builtin_amdgcn_mfma_f32_32x32x16_bf16(P1.v, v11, o1, 0, 0, 0);
#pragma unroll
            for (int c = 0; c < 4; ++c) kcur[c] = knx[c];
        } else if (kt < 8 || kt - 8 <= s) {
            // slot reuse distance is 8 kt: zero on first crossing past diag
            f32x4 z; z[0]=0.f; z[1]=0.f; z[2]=0.f; z[3]=0.f;
#pragma unroll
            for (int a = 0; a < 4; ++a)
                *(f32x4*)&buf[lq * 128 + wid * 32 + ((4 * g + 8 * a) ^ swz)] = z;
        }
        barrier_lgkm();
        // flush buf (interleaves with next panel's compute; NT fire-and-forget)
#pragma unroll
        for (int j2 = 0; j2 < 4; ++j2) {
            const int row = wid * 8 + j2 * 2 + (lane >> 5);
            const int c   = (lane & 31) * 4;
            f32x4 w = *(const f32x4*)&buf[row * 128 + (c ^ ((row & 7) << 2))];
            __builtin_nontemporal_store(w,
                (f32x4*)(attn + ((size_t)bh * Tn + qbase + row) * Tn + p * 128 + c));
        }
    }
    barrier_lgkm();   // last flush's LDS reads done before overlay reuse

    // ---- combine 4 waves' O via P2 overlay; wave 0 writes heads ----
    if (wid) {
#pragma unroll
        for (int r = 0; r < 16; ++r) {
            const int tr = (r & 3) + 8 * (r >> 2) + 4 * g;
            P2[(wid - 1) * 2048 + tr * 64 + lq]      = o0[r];
            P2[(wid - 1) * 2048 + tr * 64 + 32 + lq] = o1[r];
        }
    }
    __syncthreads();
    if (!wid) {
        const int b = bh / Hn, hh = bh % Hn;
#pragma unroll
        for (int r = 0; r < 16; ++r) {
            const int tr = (r & 3) + 8 * (r >> 2) + 4 * g;
            float* base = heads + ((size_t)(b * Tn + (qbase + tr))) * Dn + hh * DHn;
            base[lq]      = o0[r] + P2[tr * 64 + lq]
                          + P2[2048 + tr * 64 + lq] + P2[4096 + tr * 64 + lq];
            base[32 + lq] = o1[r] + P2[tr * 64 + 32 + lq]
                          + P2[2048 + tr * 64 + 32 + lq] + P2[4096 + tr * 64 + 32 + lq];
        }
    }
}

extern "C" void kernel_launch(void* const* d_in, const int* in_sizes, int n_in,
                              void* d_out, int out_size, void* d_ws, size_t ws_size,
                              hipStream_t stream) {
    (void)in_sizes; (void)n_in; (void)out_size; (void)ws_size;
    const float* x  = (const float*)d_in[0];
    const float* Wq = (const float*)d_in[1];
    const float* bq = (const float*)d_in[2];
    const float* Wk = (const float*)d_in[3];
    const float* bk = (const float*)d_in[4];
    const float* Wv = (const float*)d_in[5];
    const float* bv = (const float*)d_in[6];
    // d_in[7] = attn_mask: structurally causal, handled in-kernel.

    float* heads = (float*)d_out;
    float* attn  = heads + (size_t)Bn * Tn * Dn;

    unsigned short* qws  = (unsigned short*)d_ws;
    unsigned short* kws  = qws + NX;   // K frag order, NX elems
    unsigned short* vtws = kws + NX;   // V frag order, NX elems

    proj_staged<<<dim3(32, 6, 3), 256, 0, stream>>>(x, Wq, Wk, Wv, bq, bk, bv,
                                                    qws, kws, vtws);
    attn_main<<<1536, 256, 0, stream>>>(qws, kws, vtws, heads, attn);
}

// Round 25
// 130.607 us; speedup vs baseline: 1.0317x; 1.0317x over previous
//
#include <hip/hip_runtime.h>

typedef float f32x16 __attribute__((ext_vector_type(16)));
typedef float f32x4  __attribute__((ext_vector_type(4)));
typedef short s16x8  __attribute__((ext_vector_type(8)));
typedef short s16x4  __attribute__((ext_vector_type(4)));

constexpr int Bn = 2, Tn = 2048, Dn = 768, Hn = 12, DHn = 64;
constexpr int NX = Bn * Tn * Dn;   // 3,145,728
constexpr int NW = Dn * Dn;        // 589,824
constexpr float SC2f = 0.125f * 1.44269504088896f;  // (1/sqrt(64))*log2(e)

__device__ __forceinline__ unsigned short f2bf(float f) {
    union { float f; unsigned int i; } c; c.f = f;
    unsigned int u = c.i;
    u += 0x7fffu + ((u >> 16) & 1u);
    return (unsigned short)(u >> 16);
}
__device__ __forceinline__ unsigned int cvtpk(float lo, float hi) {
    unsigned int r;
    asm("v_cvt_pk_bf16_f32 %0, %1, %2" : "=v"(r) : "v"(lo), "v"(hi));
    return r;
}
// raw v_exp_f32 (inputs are well within the normal range; tolerance 7e-2)
__device__ __forceinline__ float fexp2(float x) {
    return __builtin_amdgcn_exp2f(x);
}
// load 8 f32 and convert to 8 bf16 in-register (RNE via cvt_pk)
__device__ __forceinline__ s16x8 ld_cvt(const float* p) {
    f32x4 a = *(const f32x4*)p;
    f32x4 b = *(const f32x4*)(p + 4);
    union { unsigned int u[4]; s16x8 v; } r;
    r.u[0] = cvtpk(a[0], a[1]); r.u[1] = cvtpk(a[2], a[3]);
    r.u[2] = cvtpk(b[0], b[1]); r.u[3] = cvtpk(b[2], b[3]);
    return r.v;
}
__device__ __forceinline__ void barrier_lgkm() {
    asm volatile("s_waitcnt lgkmcnt(0)" ::: "memory");
    __builtin_amdgcn_s_barrier();
    asm volatile("" ::: "memory");
}

// ---- LDS-staged QKV projection from f32 inputs (cvt fused in staging):
// 128x128 tile, BK=32, double-buffered.
// z=0: Q row-layout [bh][t][dh] (scaled). z=1: K in MFMA-FRAGMENT order
// Kf[bh][kt][c][lane][8]. z=2: V in fragment order Vf[bh][kt][c2][o][lane][8].
__global__ __launch_bounds__(256) void proj_staged(
    const float* __restrict__ x,
    const float* __restrict__ wq, const float* __restrict__ wk,
    const float* __restrict__ wv,
    const float* __restrict__ bq, const float* __restrict__ bk,
    const float* __restrict__ bv,
    unsigned short* __restrict__ qo, unsigned short* __restrict__ kfo,
    unsigned short* __restrict__ vfo)
{
    __shared__ unsigned short lA[2][128 * 40];
    __shared__ unsigned short lB[2][128 * 40];

    const int z = blockIdx.z;
    const bool vt = (z == 2);
    const float* W = (z == 0) ? wq : (z == 1) ? wk : wv;
    const float* bias = (z == 0) ? bq : (z == 1) ? bk : bv;
    const int tid = threadIdx.x, lane = tid & 63, wid = tid >> 6;
    const int lq = lane & 31, g = lane >> 5;
    const int mb = vt ? blockIdx.y : blockIdx.x;
    const int nb = vt ? blockIdx.x : blockIdx.y;
    const float* Am = vt ? W : x;
    const float* Bm = vt ? x : W;

    const int srow = tid >> 2, sch = tid & 3;
    const float* ag0 = Am + (size_t)(mb * 128 +      srow) * Dn + sch * 8;
    const float* ag1 = Am + (size_t)(mb * 128 + 64 + srow) * Dn + sch * 8;
    const float* bg0 = Bm + (size_t)(nb * 128 +      srow) * Dn + sch * 8;
    const float* bg1 = Bm + (size_t)(nb * 128 + 64 + srow) * Dn + sch * 8;
    const int sd0 = srow * 40 + sch * 8;
    const int sd1 = (64 + srow) * 40 + sch * 8;

    f32x16 acc[2][2];
#pragma unroll
    for (int am = 0; am < 2; ++am)
#pragma unroll
        for (int bn = 0; bn < 2; ++bn)
#pragma unroll
            for (int i = 0; i < 16; ++i) acc[am][bn][i] = 0.f;

    {
        s16x8 a0 = ld_cvt(ag0), a1 = ld_cvt(ag1);
        s16x8 b0 = ld_cvt(bg0), b1 = ld_cvt(bg1);
        *(s16x8*)&lA[0][sd0] = a0; *(s16x8*)&lA[0][sd1] = a1;
        *(s16x8*)&lB[0][sd0] = b0; *(s16x8*)&lB[0][sd1] = b1;
    }
    const int ar = (wid & 1) * 64 + lq;
    const int br = (wid >> 1) * 64 + lq;

    for (int kt = 0; kt < 24; ++kt) {
        const int cur = kt & 1;
        s16x8 a0, a1, b0, b1;
        if (kt < 23) {
            a0 = ld_cvt(ag0 + (kt + 1) * 32);
            a1 = ld_cvt(ag1 + (kt + 1) * 32);
            b0 = ld_cvt(bg0 + (kt + 1) * 32);
            b1 = ld_cvt(bg1 + (kt + 1) * 32);
        }
        barrier_lgkm();
        s16x8 afr[2][2], bfr[2][2];
#pragma unroll
        for (int am = 0; am < 2; ++am)
#pragma unroll
            for (int kc = 0; kc < 2; ++kc)
                afr[am][kc] = *(const s16x8*)&lA[cur][(ar + am * 32) * 40 + (2 * kc + g) * 8];
#pragma unroll
        for (int bn = 0; bn < 2; ++bn)
#pragma unroll
            for (int kc = 0; kc < 2; ++kc)
                bfr[bn][kc] = *(const s16x8*)&lB[cur][(br + bn * 32) * 40 + (2 * kc + g) * 8];
#pragma unroll
        for (int kc = 0; kc < 2; ++kc)
#pragma unroll
            for (int am = 0; am < 2; ++am)
#pragma unroll
                for (int bn = 0; bn < 2; ++bn)
                    acc[am][bn] = __builtin_amdgcn_mfma_f32_32x32x16_bf16(
                        afr[am][kc], bfr[bn][kc], acc[am][bn], 0, 0, 0);
        if (kt < 23) {
            *(s16x8*)&lA[cur ^ 1][sd0] = a0; *(s16x8*)&lA[cur ^ 1][sd1] = a1;
            *(s16x8*)&lB[cur ^ 1][sd0] = b0; *(s16x8*)&lB[cur ^ 1][sd1] = b1;
        }
    }

    if (z == 0) {          // Q: row layout, pre-scaled
#pragma unroll
        for (int bn = 0; bn < 2; ++bn) {
            const int e = nb * 128 + (wid >> 1) * 64 + bn * 32 + lq;
            const float bvl = bias[e];
            const int h = e >> 6, dh = e & 63;
#pragma unroll
            for (int am = 0; am < 2; ++am)
#pragma unroll
                for (int r = 0; r < 16; ++r) {
                    const int t = mb * 128 + (wid & 1) * 64 + am * 32 + ((r & 3) + 8 * (r >> 2) + 4 * g);
                    const int b = t >> 11, tl = t & (Tn - 1);
                    qo[((size_t)(b * Hn + h) * Tn + tl) * DHn + dh] = f2bf((acc[am][bn][r] + bvl) * SC2f);
                }
        }
    } else if (z == 1) {   // K: fragment order
#pragma unroll
        for (int bn = 0; bn < 2; ++bn) {
            const int e = nb * 128 + (wid >> 1) * 64 + bn * 32 + lq;
            const float bvl = bias[e];
            const int h = e >> 6, dh = e & 63;
            const int cK = dh >> 4, gK = (dh >> 3) & 1, el = dh & 7;
#pragma unroll
            for (int am = 0; am < 2; ++am)
#pragma unroll
                for (int r = 0; r < 16; ++r) {
                    const int t = mb * 128 + (wid & 1) * 64 + am * 32 + ((r & 3) + 8 * (r >> 2) + 4 * g);
                    const int b = t >> 11, tl = t & (Tn - 1);
                    const int kt2 = tl >> 5, lrow = tl & 31;
                    kfo[(((size_t)(b * Hn + h) * 64 + kt2) * 4 + cK) * 512
                        + (lrow + 32 * gK) * 8 + el] = f2bf(acc[am][bn][r] + bvl);
                }
        }
    } else {               // V: fragment order (values are V^T[e][t])
#pragma unroll
        for (int am = 0; am < 2; ++am)
#pragma unroll
            for (int r = 0; r < 16; ++r) {
                const int e = mb * 128 + (wid & 1) * 64 + am * 32 + ((r & 3) + 8 * (r >> 2) + 4 * g);
                const float bvl = bias[e];
                const int h = e >> 6, dhp = e & 63;
                const int o = dhp >> 5, lqv = dhp & 31;
#pragma unroll
                for (int bn = 0; bn < 2; ++bn) {
                    const int t = nb * 128 + (wid >> 1) * 64 + bn * 32 + lq;
                    const int b = t >> 11, tl = t & (Tn - 1);
                    const int kt2 = tl >> 5, kcol = tl & 31;
                    const int c2 = kcol >> 4, rem = kcol & 15;
                    const int gV = (rem >> 2) & 1;
                    const int j = (rem & 3) + ((rem >> 3) << 2);
                    vfo[((((size_t)(b * Hn + h) * 64 + kt2) * 2 + c2) * 2 + o) * 512
                        + (lqv + 32 * gV) * 8 + j] = f2bf(acc[am][bn][r] + bvl);
                }
            }
    }
}

// ---- main attention: prepass + double-buffered panel NT writes.
// __launch_bounds__(256,4): <=128 VGPR -> 4 waves/SIMD. Diag masking in a
// wave-uniform branch. exp2 is raw v_exp_f32 (libm exp2f expands to ~6-10
// instrs; 16/tile x 200k tile-passes made it the top VALU consumer).
__global__ __launch_bounds__(256, 4) void attn_main(
    const unsigned short* __restrict__ Q,   // [BH][T][Dh], pre-scaled
    const unsigned short* __restrict__ Kf,  // [BH][64][4][64][8] frag order
    const unsigned short* __restrict__ Vf,  // [BH][64][2][2][64][8] frag order
    float* __restrict__ heads,              // [B][T][H][Dh]
    float* __restrict__ attn)               // [BH][T][T]
{
    __shared__ float P2[8192];              // 2 x 16KB panels; O-combine overlay
    __shared__ float pls[4][32];

    const int tid = threadIdx.x, lane = tid & 63, wid = tid >> 6;
    const int lq = lane & 31, g = lane >> 5;
    // 1536 blocks: XCD k owns heads [3k,3k+3); longest strips first.
    const int n2 = ((int)blockIdx.x & 7) * 192 + ((int)blockIdx.x >> 3);
    const int bh = n2 >> 6;
    const int s  = 63 - (n2 & 63);
    const int qbase = s * 32;

    const unsigned short* Qb = Q  + ((size_t)bh * Tn + qbase) * DHn;
    const unsigned short* Kb = Kf + (size_t)bh * 131072 + lane * 8;
    const unsigned short* Vb = Vf + (size_t)bh * 131072 + lane * 8;
    const int swz = (lq & 7) << 2;

    s16x8 qf[4];
#pragma unroll
    for (int c = 0; c < 4; ++c)
        qf[c] = *(const s16x8*)(Qb + lq * DHn + c * 16 + g * 8);

    // ---- prepass: block-local softmax denominator ----
    float ls = 0.f;
    for (int kt = wid; kt <= s; kt += 4) {
        const unsigned short* kb = Kb + (size_t)kt * 2048;
        f32x16 acc;
#pragma unroll
        for (int i = 0; i < 16; ++i) acc[i] = 0.f;
#pragma unroll
        for (int c = 0; c < 4; ++c)
            acc = __builtin_amdgcn_mfma_f32_32x32x16_bf16(
                *(const s16x8*)(kb + c * 512), qf[c], acc, 0, 0, 0);
        if (kt == s) {      // wave-uniform: only the diagonal tile masks
#pragma unroll
            for (int r = 0; r < 16; ++r) {
                const int koff = (r & 3) + 8 * (r >> 2) + 4 * g;
                ls += (koff <= lq) ? fexp2(acc[r]) : 0.f;
            }
        } else {
#pragma unroll
            for (int r = 0; r < 16; ++r) ls += fexp2(acc[r]);
        }
    }
    ls += __shfl_xor(ls, 32);
    if (g == 0) pls[wid][lq] = ls;
    __syncthreads();
    const float rl = 1.f / (pls[0][lq] + pls[1][lq] + pls[2][lq] + pls[3][lq]);

    f32x16 o0, o1;
#pragma unroll
    for (int i = 0; i < 16; ++i) { o0[i] = 0.f; o1[i] = 0.f; }

    // ---- main loop: 16 panels x 4 tiles, double-buffered ----
    for (int p = 0; p < 16; ++p) {
        float* buf = P2 + (p & 1) * 4096;
        const int kt = p * 4 + wid;       // this wave's tile; slot == wid
        if (kt <= s) {
            const unsigned short* kb = Kb + (size_t)kt * 2048;
            f32x16 acc;
#pragma unroll
            for (int i = 0; i < 16; ++i) acc[i] = 0.f;
#pragma unroll
            for (int c = 0; c < 4; ++c)
                acc = __builtin_amdgcn_mfma_f32_32x32x16_bf16(
                    *(const s16x8*)(kb + c * 512), qf[c], acc, 0, 0, 0);
            float pv[16];
            if (kt == s) {  // wave-uniform diag branch: mask only here
#pragma unroll
                for (int r = 0; r < 16; ++r) {
                    const int koff = (r & 3) + 8 * (r >> 2) + 4 * g;
                    pv[r] = (koff <= lq) ? fexp2(acc[r]) * rl : 0.f;
                }
            } else {
#pragma unroll
                for (int r = 0; r < 16; ++r) pv[r] = fexp2(acc[r]) * rl;
            }
            // P-tile into panel slot wid (row lq, swizzled within 32-col slot)
#pragma unroll
            for (int a = 0; a < 4; ++a) {
                f32x4 w;
                w[0]=pv[4*a+0]; w[1]=pv[4*a+1]; w[2]=pv[4*a+2]; w[3]=pv[4*a+3];
                *(f32x4*)&buf[lq * 128 + wid * 32 + ((4 * g + 8 * a) ^ swz)] = w;
            }
            // PV: P (bf16) via cvt_pk; V fragments pre-packed
            union { unsigned int uu[4]; s16x8 v; } P0, P1;
            P0.uu[0]=cvtpk(pv[0],pv[1]);   P0.uu[1]=cvtpk(pv[2],pv[3]);
            P0.uu[2]=cvtpk(pv[4],pv[5]);   P0.uu[3]=cvtpk(pv[6],pv[7]);
            P1.uu[0]=cvtpk(pv[8],pv[9]);   P1.uu[1]=cvtpk(pv[10],pv[11]);
            P1.uu[2]=cvtpk(pv[12],pv[13]); P1.uu[3]=cvtpk(pv[14],pv[15]);
            const unsigned short* vb = Vb + (size_t)kt * 2048;
#pragma unroll
            for (int c2 = 0; c2 < 2; ++c2) {
                const s16x8 pa = c2 ? P1.v : P0.v;
                o0 = __builtin_amdgcn_mfma_f32_32x32x16_bf16(
                    pa, *(const s16x8*)(vb + (c2 * 2 + 0) * 512), o0, 0, 0, 0);
                o1 = __builtin_amdgcn_mfma_f32_32x32x16_bf16(
                    pa, *(const s16x8*)(vb + (c2 * 2 + 1) * 512), o1, 0, 0, 0);
            }
        } else if (kt < 8 || kt - 8 <= s) {
            // slot reuse distance is 8 kt: zero on first crossing past diag
            f32x4 z; z[0]=0.f; z[1]=0.f; z[2]=0.f; z[3]=0.f;
#pragma unroll
            for (int a = 0; a < 4; ++a)
                *(f32x4*)&buf[lq * 128 + wid * 32 + ((4 * g + 8 * a) ^ swz)] = z;
        }
        barrier_lgkm();
        // flush buf (interleaves with next panel's compute; NT fire-and-forget)
#pragma unroll
        for (int j2 = 0; j2 < 4; ++j2) {
            const int row = wid * 8 + j2 * 2 + (lane >> 5);
            const int c   = (lane & 31) * 4;
            f32x4 w = *(const f32x4*)&buf[row * 128 + (c ^ ((row & 7) << 2))];
            __builtin_nontemporal_store(w,
                (f32x4*)(attn + ((size_t)bh * Tn + qbase + row) * Tn + p * 128 + c));
        }
    }
    barrier_lgkm();   // last flush's LDS reads done before overlay reuse

    // ---- combine 4 waves' O via P2 overlay; wave 0 writes heads ----
    if (wid) {
#pragma unroll
        for (int r = 0; r < 16; ++r) {
            const int tr = (r & 3) + 8 * (r >> 2) + 4 * g;
            P2[(wid - 1) * 2048 + tr * 64 + lq]      = o0[r];
            P2[(wid - 1) * 2048 + tr * 64 + 32 + lq] = o1[r];
        }
    }
    __syncthreads();
    if (!wid) {
        const int b = bh / Hn, hh = bh % Hn;
#pragma unroll
        for (int r = 0; r < 16; ++r) {
            const int tr = (r & 3) + 8 * (r >> 2) + 4 * g;
            float* base = heads + ((size_t)(b * Tn + (qbase + tr))) * Dn + hh * DHn;
            base[lq]      = o0[r] + P2[tr * 64 + lq]
                          + P2[2048 + tr * 64 + lq] + P2[4096 + tr * 64 + lq];
            base[32 + lq] = o1[r] + P2[tr * 64 + 32 + lq]
                          + P2[2048 + tr * 64 + 32 + lq] + P2[4096 + tr * 64 + 32 + lq];
        }
    }
}

extern "C" void kernel_launch(void* const* d_in, const int* in_sizes, int n_in,
                              void* d_out, int out_size, void* d_ws, size_t ws_size,
                              hipStream_t stream) {
    (void)in_sizes; (void)n_in; (void)out_size; (void)ws_size;
    const float* x  = (const float*)d_in[0];
    const float* Wq = (const float*)d_in[1];
    const float* bq = (const float*)d_in[2];
    const float* Wk = (const float*)d_in[3];
    const float* bk = (const float*)d_in[4];
    const float* Wv = (const float*)d_in[5];
    const float* bv = (const float*)d_in[6];
    // d_in[7] = attn_mask: structurally causal, handled in-kernel.

    float* heads = (float*)d_out;
    float* attn  = heads + (size_t)Bn * Tn * Dn;

    unsigned short* qws  = (unsigned short*)d_ws;
    unsigned short* kws  = qws + NX;   // K frag order, NX elems
    unsigned short* vtws = kws + NX;   // V frag order, NX elems

    proj_staged<<<dim3(32, 6, 3), 256, 0, stream>>>(x, Wq, Wk, Wv, bq, bk, bv,
                                                    qws, kws, vtws);
    attn_main<<<1536, 256, 0, stream>>>(qws, kws, vtws, heads, attn);
}

// Round 26
// 126.675 us; speedup vs baseline: 1.0638x; 1.0310x over previous
//
#include <hip/hip_runtime.h>

typedef float f32x16 __attribute__((ext_vector_type(16)));
typedef float f32x4  __attribute__((ext_vector_type(4)));
typedef short s16x8  __attribute__((ext_vector_type(8)));
typedef short s16x4  __attribute__((ext_vector_type(4)));

constexpr int Bn = 2, Tn = 2048, Dn = 768, Hn = 12, DHn = 64;
constexpr int NX = Bn * Tn * Dn;   // 3,145,728
constexpr int NW = Dn * Dn;        // 589,824
constexpr float SC2f = 0.125f * 1.44269504088896f;  // (1/sqrt(64))*log2(e)

__device__ __forceinline__ unsigned short f2bf(float f) {
    union { float f; unsigned int i; } c; c.f = f;
    unsigned int u = c.i;
    u += 0x7fffu + ((u >> 16) & 1u);
    return (unsigned short)(u >> 16);
}
__device__ __forceinline__ unsigned int cvtpk(float lo, float hi) {
    unsigned int r;
    asm("v_cvt_pk_bf16_f32 %0, %1, %2" : "=v"(r) : "v"(lo), "v"(hi));
    return r;
}
// raw v_exp_f32 (inputs are well within the normal range; tolerance 7e-2)
__device__ __forceinline__ float fexp2(float x) {
    return __builtin_amdgcn_exp2f(x);
}
// load 8 f32 and convert to 8 bf16 in-register (RNE via cvt_pk)
__device__ __forceinline__ s16x8 ld_cvt(const float* p) {
    f32x4 a = *(const f32x4*)p;
    f32x4 b = *(const f32x4*)(p + 4);
    union { unsigned int u[4]; s16x8 v; } r;
    r.u[0] = cvtpk(a[0], a[1]); r.u[1] = cvtpk(a[2], a[3]);
    r.u[2] = cvtpk(b[0], b[1]); r.u[3] = cvtpk(b[2], b[3]);
    return r.v;
}
__device__ __forceinline__ void barrier_lgkm() {
    asm volatile("s_waitcnt lgkmcnt(0)" ::: "memory");
    __builtin_amdgcn_s_barrier();
    asm volatile("" ::: "memory");
}

// ---- LDS-staged QKV projection from f32 inputs (cvt fused in staging):
// 128x128 tile, BK=32, double-buffered.
// z=0: Q row-layout [bh][t][dh] (scaled). z=1: K in MFMA-FRAGMENT order
// Kf[bh][kt][c][lane][8]. z=2: V in fragment order Vf[bh][kt][c2][o][lane][8].
__global__ __launch_bounds__(256) void proj_staged(
    const float* __restrict__ x,
    const float* __restrict__ wq, const float* __restrict__ wk,
    const float* __restrict__ wv,
    const float* __restrict__ bq, const float* __restrict__ bk,
    const float* __restrict__ bv,
    unsigned short* __restrict__ qo, unsigned short* __restrict__ kfo,
    unsigned short* __restrict__ vfo)
{
    __shared__ unsigned short lA[2][128 * 40];
    __shared__ unsigned short lB[2][128 * 40];

    const int z = blockIdx.z;
    const bool vt = (z == 2);
    const float* W = (z == 0) ? wq : (z == 1) ? wk : wv;
    const float* bias = (z == 0) ? bq : (z == 1) ? bk : bv;
    const int tid = threadIdx.x, lane = tid & 63, wid = tid >> 6;
    const int lq = lane & 31, g = lane >> 5;
    const int mb = vt ? blockIdx.y : blockIdx.x;
    const int nb = vt ? blockIdx.x : blockIdx.y;
    const float* Am = vt ? W : x;
    const float* Bm = vt ? x : W;

    const int srow = tid >> 2, sch = tid & 3;
    const float* ag0 = Am + (size_t)(mb * 128 +      srow) * Dn + sch * 8;
    const float* ag1 = Am + (size_t)(mb * 128 + 64 + srow) * Dn + sch * 8;
    const float* bg0 = Bm + (size_t)(nb * 128 +      srow) * Dn + sch * 8;
    const float* bg1 = Bm + (size_t)(nb * 128 + 64 + srow) * Dn + sch * 8;
    const int sd0 = srow * 40 + sch * 8;
    const int sd1 = (64 + srow) * 40 + sch * 8;

    f32x16 acc[2][2];
#pragma unroll
    for (int am = 0; am < 2; ++am)
#pragma unroll
        for (int bn = 0; bn < 2; ++bn)
#pragma unroll
            for (int i = 0; i < 16; ++i) acc[am][bn][i] = 0.f;

    {
        s16x8 a0 = ld_cvt(ag0), a1 = ld_cvt(ag1);
        s16x8 b0 = ld_cvt(bg0), b1 = ld_cvt(bg1);
        *(s16x8*)&lA[0][sd0] = a0; *(s16x8*)&lA[0][sd1] = a1;
        *(s16x8*)&lB[0][sd0] = b0; *(s16x8*)&lB[0][sd1] = b1;
    }
    const int ar = (wid & 1) * 64 + lq;
    const int br = (wid >> 1) * 64 + lq;

    for (int kt = 0; kt < 24; ++kt) {
        const int cur = kt & 1;
        s16x8 a0, a1, b0, b1;
        if (kt < 23) {
            a0 = ld_cvt(ag0 + (kt + 1) * 32);
            a1 = ld_cvt(ag1 + (kt + 1) * 32);
            b0 = ld_cvt(bg0 + (kt + 1) * 32);
            b1 = ld_cvt(bg1 + (kt + 1) * 32);
        }
        barrier_lgkm();
        s16x8 afr[2][2], bfr[2][2];
#pragma unroll
        for (int am = 0; am < 2; ++am)
#pragma unroll
            for (int kc = 0; kc < 2; ++kc)
                afr[am][kc] = *(const s16x8*)&lA[cur][(ar + am * 32) * 40 + (2 * kc + g) * 8];
#pragma unroll
        for (int bn = 0; bn < 2; ++bn)
#pragma unroll
            for (int kc = 0; kc < 2; ++kc)
                bfr[bn][kc] = *(const s16x8*)&lB[cur][(br + bn * 32) * 40 + (2 * kc + g) * 8];
#pragma unroll
        for (int kc = 0; kc < 2; ++kc)
#pragma unroll
            for (int am = 0; am < 2; ++am)
#pragma unroll
                for (int bn = 0; bn < 2; ++bn)
                    acc[am][bn] = __builtin_amdgcn_mfma_f32_32x32x16_bf16(
                        afr[am][kc], bfr[bn][kc], acc[am][bn], 0, 0, 0);
        if (kt < 23) {
            *(s16x8*)&lA[cur ^ 1][sd0] = a0; *(s16x8*)&lA[cur ^ 1][sd1] = a1;
            *(s16x8*)&lB[cur ^ 1][sd0] = b0; *(s16x8*)&lB[cur ^ 1][sd1] = b1;
        }
    }

    if (z == 0) {          // Q: row layout, pre-scaled
#pragma unroll
        for (int bn = 0; bn < 2; ++bn) {
            const int e = nb * 128 + (wid >> 1) * 64 + bn * 32 + lq;
            const float bvl = bias[e];
            const int h = e >> 6, dh = e & 63;
#pragma unroll
            for (int am = 0; am < 2; ++am)
#pragma unroll
                for (int r = 0; r < 16; ++r) {
                    const int t = mb * 128 + (wid & 1) * 64 + am * 32 + ((r & 3) + 8 * (r >> 2) + 4 * g);
                    const int b = t >> 11, tl = t & (Tn - 1);
                    qo[((size_t)(b * Hn + h) * Tn + tl) * DHn + dh] = f2bf((acc[am][bn][r] + bvl) * SC2f);
                }
        }
    } else if (z == 1) {   // K: fragment order
#pragma unroll
        for (int bn = 0; bn < 2; ++bn) {
            const int e = nb * 128 + (wid >> 1) * 64 + bn * 32 + lq;
            const float bvl = bias[e];
            const int h = e >> 6, dh = e & 63;
            const int cK = dh >> 4, gK = (dh >> 3) & 1, el = dh & 7;
#pragma unroll
            for (int am = 0; am < 2; ++am)
#pragma unroll
                for (int r = 0; r < 16; ++r) {
                    const int t = mb * 128 + (wid & 1) * 64 + am * 32 + ((r & 3) + 8 * (r >> 2) + 4 * g);
                    const int b = t >> 11, tl = t & (Tn - 1);
                    const int kt2 = tl >> 5, lrow = tl & 31;
                    kfo[(((size_t)(b * Hn + h) * 64 + kt2) * 4 + cK) * 512
                        + (lrow + 32 * gK) * 8 + el] = f2bf(acc[am][bn][r] + bvl);
                }
        }
    } else {               // V: fragment order (values are V^T[e][t])
#pragma unroll
        for (int am = 0; am < 2; ++am)
#pragma unroll
            for (int r = 0; r < 16; ++r) {
                const int e = mb * 128 + (wid & 1) * 64 + am * 32 + ((r & 3) + 8 * (r >> 2) + 4 * g);
                const float bvl = bias[e];
                const int h = e >> 6, dhp = e & 63;
                const int o = dhp >> 5, lqv = dhp & 31;
#pragma unroll
                for (int bn = 0; bn < 2; ++bn) {
                    const int t = nb * 128 + (wid >> 1) * 64 + bn * 32 + lq;
                    const int b = t >> 11, tl = t & (Tn - 1);
                    const int kt2 = tl >> 5, kcol = tl & 31;
                    const int c2 = kcol >> 4, rem = kcol & 15;
                    const int gV = (rem >> 2) & 1;
                    const int j = (rem & 3) + ((rem >> 3) << 2);
                    vfo[((((size_t)(b * Hn + h) * 64 + kt2) * 2 + c2) * 2 + o) * 512
                        + (lqv + 32 * gV) * 8 + j] = f2bf(acc[am][bn][r] + bvl);
                }
            }
    }
}

// ---- main attention: prepass + double-buffered panel NT writes.
// __launch_bounds__(256,4): <=128 VGPR -> 4 waves/SIMD. Diag masking in a
// wave-uniform branch. exp2 is raw v_exp_f32 (libm exp2f expands to ~6-10
// instrs; 16/tile x 200k tile-passes made it the top VALU consumer).
__global__ __launch_bounds__(256, 4) void attn_main(
    const unsigned short* __restrict__ Q,   // [BH][T][Dh], pre-scaled
    const unsigned short* __restrict__ Kf,  // [BH][64][4][64][8] frag order
    const unsigned short* __restrict__ Vf,  // [BH][64][2][2][64][8] frag order
    float* __restrict__ heads,              // [B][T][H][Dh]
    float* __restrict__ attn)               // [BH][T][T]
{
    __shared__ float P2[8192];              // 2 x 16KB panels; O-combine overlay
    __shared__ float pls[4][32];

    const int tid = threadIdx.x, lane = tid & 63, wid = tid >> 6;
    const int lq = lane & 31, g = lane >> 5;
    // 1536 blocks: XCD k owns heads [3k,3k+3); longest strips first.
    const int n2 = ((int)blockIdx.x & 7) * 192 + ((int)blockIdx.x >> 3);
    const int bh = n2 >> 6;
    const int s  = 63 - (n2 & 63);
    const int qbase = s * 32;

    const unsigned short* Qb = Q  + ((size_t)bh * Tn + qbase) * DHn;
    const unsigned short* Kb = Kf + (size_t)bh * 131072 + lane * 8;
    const unsigned short* Vb = Vf + (size_t)bh * 131072 + lane * 8;
    const int swz = (lq & 7) << 2;

    s16x8 qf[4];
#pragma unroll
    for (int c = 0; c < 4; ++c)
        qf[c] = *(const s16x8*)(Qb + lq * DHn + c * 16 + g * 8);

    // ---- prepass: block-local softmax denominator ----
    float ls = 0.f;
    for (int kt = wid; kt <= s; kt += 4) {
        const unsigned short* kb = Kb + (size_t)kt * 2048;
        f32x16 acc;
#pragma unroll
        for (int i = 0; i < 16; ++i) acc[i] = 0.f;
#pragma unroll
        for (int c = 0; c < 4; ++c)
            acc = __builtin_amdgcn_mfma_f32_32x32x16_bf16(
                *(const s16x8*)(kb + c * 512), qf[c], acc, 0, 0, 0);
        if (kt == s) {      // wave-uniform: only the diagonal tile masks
#pragma unroll
            for (int r = 0; r < 16; ++r) {
                const int koff = (r & 3) + 8 * (r >> 2) + 4 * g;
                ls += (koff <= lq) ? fexp2(acc[r]) : 0.f;
            }
        } else {
#pragma unroll
            for (int r = 0; r < 16; ++r) ls += fexp2(acc[r]);
        }
    }
    ls += __shfl_xor(ls, 32);
    if (g == 0) pls[wid][lq] = ls;
    __syncthreads();
    const float rl = 1.f / (pls[0][lq] + pls[1][lq] + pls[2][lq] + pls[3][lq]);

    f32x16 o0, o1;
#pragma unroll
    for (int i = 0; i < 16; ++i) { o0[i] = 0.f; o1[i] = 0.f; }

    // ---- main loop: 16 panels x 4 tiles, double-buffered ----
    for (int p = 0; p < 16; ++p) {
        float* buf = P2 + (p & 1) * 4096;
        const int kt = p * 4 + wid;       // this wave's tile; slot == wid
        if (kt <= s) {
            const unsigned short* kb = Kb + (size_t)kt * 2048;
            f32x16 acc;
#pragma unroll
            for (int i = 0; i < 16; ++i) acc[i] = 0.f;
#pragma unroll
            for (int c = 0; c < 4; ++c)
                acc = __builtin_amdgcn_mfma_f32_32x32x16_bf16(
                    *(const s16x8*)(kb + c * 512), qf[c], acc, 0, 0, 0);
            float pv[16];
            if (kt == s) {  // wave-uniform diag branch: mask only here
#pragma unroll
                for (int r = 0; r < 16; ++r) {
                    const int koff = (r & 3) + 8 * (r >> 2) + 4 * g;
                    pv[r] = (koff <= lq) ? fexp2(acc[r]) * rl : 0.f;
                }
            } else {
#pragma unroll
                for (int r = 0; r < 16; ++r) pv[r] = fexp2(acc[r]) * rl;
            }
            // P-tile into panel slot wid (row lq, swizzled within 32-col slot)
#pragma unroll
            for (int a = 0; a < 4; ++a) {
                f32x4 w;
                w[0]=pv[4*a+0]; w[1]=pv[4*a+1]; w[2]=pv[4*a+2]; w[3]=pv[4*a+3];
                *(f32x4*)&buf[lq * 128 + wid * 32 + ((4 * g + 8 * a) ^ swz)] = w;
            }
            // PV: P (bf16) via cvt_pk; V fragments pre-packed
            union { unsigned int uu[4]; s16x8 v; } P0, P1;
            P0.uu[0]=cvtpk(pv[0],pv[1]);   P0.uu[1]=cvtpk(pv[2],pv[3]);
            P0.uu[2]=cvtpk(pv[4],pv[5]);   P0.uu[3]=cvtpk(pv[6],pv[7]);
            P1.uu[0]=cvtpk(pv[8],pv[9]);   P1.uu[1]=cvtpk(pv[10],pv[11]);
            P1.uu[2]=cvtpk(pv[12],pv[13]); P1.uu[3]=cvtpk(pv[14],pv[15]);
            const unsigned short* vb = Vb + (size_t)kt * 2048;
#pragma unroll
            for (int c2 = 0; c2 < 2; ++c2) {
                const s16x8 pa = c2 ? P1.v : P0.v;
                o0 = __builtin_amdgcn_mfma_f32_32x32x16_bf16(
                    pa, *(const s16x8*)(vb + (c2 * 2 + 0) * 512), o0, 0, 0, 0);
                o1 = __builtin_amdgcn_mfma_f32_32x32x16_bf16(
                    pa, *(const s16x8*)(vb + (c2 * 2 + 1) * 512), o1, 0, 0, 0);
            }
        } else if (kt < 8 || kt - 8 <= s) {
            // slot reuse distance is 8 kt: zero on first crossing past diag
            f32x4 z; z[0]=0.f; z[1]=0.f; z[2]=0.f; z[3]=0.f;
#pragma unroll
            for (int a = 0; a < 4; ++a)
                *(f32x4*)&buf[lq * 128 + wid * 32 + ((4 * g + 8 * a) ^ swz)] = z;
        }
        barrier_lgkm();
        // flush buf (interleaves with next panel's compute; NT fire-and-forget)
#pragma unroll
        for (int j2 = 0; j2 < 4; ++j2) {
            const int row = wid * 8 + j2 * 2 + (lane >> 5);
            const int c   = (lane & 31) * 4;
            f32x4 w = *(const f32x4*)&buf[row * 128 + (c ^ ((row & 7) << 2))];
            __builtin_nontemporal_store(w,
                (f32x4*)(attn + ((size_t)bh * Tn + qbase + row) * Tn + p * 128 + c));
        }
    }
    barrier_lgkm();   // last flush's LDS reads done before overlay reuse

    // ---- combine 4 waves' O via P2 overlay; wave 0 writes heads ----
    if (wid) {
#pragma unroll
        for (int r = 0; r < 16; ++r) {
            const int tr = (r & 3) + 8 * (r >> 2) + 4 * g;
            P2[(wid - 1) * 2048 + tr * 64 + lq]      = o0[r];
            P2[(wid - 1) * 2048 + tr * 64 + 32 + lq] = o1[r];
        }
    }
    __syncthreads();
    if (!wid) {
        const int b = bh / Hn, hh = bh % Hn;
#pragma unroll
        for (int r = 0; r < 16; ++r) {
            const int tr = (r & 3) + 8 * (r >> 2) + 4 * g;
            float* base = heads + ((size_t)(b * Tn + (qbase + tr))) * Dn + hh * DHn;
            base[lq]      = o0[r] + P2[tr * 64 + lq]
                          + P2[2048 + tr * 64 + lq] + P2[4096 + tr * 64 + lq];
            base[32 + lq] = o1[r] + P2[tr * 64 + 32 + lq]
                          + P2[2048 + tr * 64 + 32 + lq] + P2[4096 + tr * 64 + 32 + lq];
        }
    }
}

extern "C" void kernel_launch(void* const* d_in, const int* in_sizes, int n_in,
                              void* d_out, int out_size, void* d_ws, size_t ws_size,
                              hipStream_t stream) {
    (void)in_sizes; (void)n_in; (void)out_size; (void)ws_size;
    const float* x  = (const float*)d_in[0];
    const float* Wq = (const float*)d_in[1];
    const float* bq = (const float*)d_in[2];
    const float* Wk = (const float*)d_in[3];
    const float* bk = (const float*)d_in[4];
    const float* Wv = (const float*)d_in[5];
    const float* bv = (const float*)d_in[6];
    // d_in[7] = attn_mask: structurally causal, handled in-kernel.

    float* heads = (float*)d_out;
    float* attn  = heads + (size_t)Bn * Tn * Dn;

    unsigned short* qws  = (unsigned short*)d_ws;
    unsigned short* kws  = qws + NX;   // K frag order, NX elems
    unsigned short* vtws = kws + NX;   // V frag order, NX elems

    proj_staged<<<dim3(32, 6, 3), 256, 0, stream>>>(x, Wq, Wk, Wv, bq, bk, bv,
                                                    qws, kws, vtws);
    attn_main<<<1536, 256, 0, stream>>>(qws, kws, vtws, heads, attn);
}